// Round 12
// baseline (463.812 us; speedup 1.0000x reference)
//
#include <hip/hip_runtime.h>
#include <math.h>

#define NPTS 4096
#define KNN 10
#define CAP 48          // group-8 bound is <=80; overflow -> exact full rescan
#define TAU_SLACK 1e-4f // covers key-vs-d2 rounding skew (~2e-6 abs)
#define NRM_N (8 * 3 * NPTS)
#define DYN_BYTES (NPTS * 16 + 128 * CAP * 2 + 512)   // 78336

__device__ __forceinline__ float med3f(float a, float b, float c) {
    return __builtin_amdgcn_fmed3f(a, b, c);
}

// ---------------- LAPACK building blocks (f32, faithful to netlib) ----------
// Verified bit-exact vs numpy/LAPACK in R1-R11 (absmax 0.0). DO NOT TOUCH.

__device__ __forceinline__ float slapy2_(float x, float y) {
    float ax = fabsf(x), ay = fabsf(y);
    float w = fmaxf(ax, ay), z = fminf(ax, ay);
    if (z == 0.f) return w;
    float t = z / w;
    return w * sqrtf(1.f + t * t);
}

__device__ __forceinline__ void slartg_(float f, float g, float* c, float* s, float* r) {
    if (g == 0.f) { *c = 1.f; *s = 0.f; *r = f; }
    else if (f == 0.f) { *c = 0.f; *s = copysignf(1.f, g); *r = fabsf(g); }
    else {
        float f1 = fabsf(f);
        float d = sqrtf(f * f + g * g);
        float rr = copysignf(d, f);
        *c = f1 / d;
        *s = g / rr;
        *r = rr;
    }
}

__device__ void slaev2_(float a, float b, float c,
                        float* rt1, float* rt2, float* cs1, float* sn1) {
    float sm = a + c;
    float df = a - c;
    float adf = fabsf(df);
    float tb = b + b;
    float ab = fabsf(tb);
    float acmx, acmn;
    if (fabsf(a) > fabsf(c)) { acmx = a; acmn = c; } else { acmx = c; acmn = a; }
    float rt;
    if (adf > ab)      { float t = ab / adf; rt = adf * sqrtf(1.f + t * t); }
    else if (adf < ab) { float t = adf / ab; rt = ab * sqrtf(1.f + t * t); }
    else               { rt = ab * sqrtf(2.f); }
    int sgn1;
    if (sm < 0.f) {
        *rt1 = 0.5f * (sm - rt); sgn1 = -1;
        *rt2 = (acmx / *rt1) * acmn - (b / *rt1) * b;
    } else if (sm > 0.f) {
        *rt1 = 0.5f * (sm + rt); sgn1 = 1;
        *rt2 = (acmx / *rt1) * acmn - (b / *rt1) * b;
    } else {
        *rt1 = 0.5f * rt; *rt2 = -0.5f * rt; sgn1 = 1;
    }
    int sgn2;
    float cs;
    if (df >= 0.f) { cs = df + rt; sgn2 = 1; } else { cs = df - rt; sgn2 = -1; }
    float acs = fabsf(cs);
    if (acs > ab) {
        float ct = -tb / cs;
        *sn1 = 1.f / sqrtf(1.f + ct * ct);
        *cs1 = ct * (*sn1);
    } else {
        if (ab == 0.f) { *cs1 = 1.f; *sn1 = 0.f; }
        else {
            float tn = -cs / tb;
            *cs1 = 1.f / sqrtf(1.f + tn * tn);
            *sn1 = tn * (*cs1);
        }
    }
    if (sgn1 == sgn2) { float tn = *cs1; *cs1 = -(*sn1); *sn1 = tn; }
}

__device__ void steqr3_(float* d, float* e, float Z[3][3]) {
    const float eps    = 5.9604644775390625e-8f;  // 2^-24
    const float eps2   = eps * eps;
    const float safmin = 1.17549435e-38f;
    const int n = 3, nm1 = 2;
    const int nmaxit = 90;
    int jtot = 0, l1 = 1;
    int guard = 0;

    while (l1 <= n) {
        if (++guard > 600) break;
        if (l1 > 1) e[l1 - 2] = 0.f;
        int m = n;
        if (l1 <= nm1) {
            for (int mm = l1; mm <= nm1; ++mm) {
                float tst = fabsf(e[mm - 1]);
                if (tst == 0.f) { m = mm; break; }
                if (tst <= (sqrtf(fabsf(d[mm - 1])) * sqrtf(fabsf(d[mm]))) * eps) {
                    e[mm - 1] = 0.f; m = mm; break;
                }
            }
        }
        int l = l1, lsv = l1, lend = m, lendsv = m;
        l1 = m + 1;
        if (lend == l) continue;
        float anorm = 0.f;
        for (int i = l; i <= lend; i++) anorm = fmaxf(anorm, fabsf(d[i - 1]));
        for (int i = l; i <= lend - 1; i++) anorm = fmaxf(anorm, fabsf(e[i - 1]));
        if (anorm == 0.f) continue;
        if (fabsf(d[lend - 1]) < fabsf(d[l - 1])) { lend = lsv; l = lendsv; }

        if (lend > l) {
            for (;;) {
                if (++guard > 600) return;
                int m2 = lend;
                if (l != lend) {
                    for (int mm = l; mm <= lend - 1; ++mm) {
                        float tst = e[mm - 1] * e[mm - 1];
                        if (tst <= (eps2 * fabsf(d[mm - 1])) * fabsf(d[mm]) + safmin) { m2 = mm; break; }
                    }
                }
                if (m2 < lend) e[m2 - 1] = 0.f;
                float p = d[l - 1];
                if (m2 == l) {
                    d[l - 1] = p; l = l + 1;
                    if (l <= lend) continue;
                    break;
                }
                if (m2 == l + 1) {
                    float rt1, rt2, c, s;
                    slaev2_(d[l - 1], e[l - 1], d[l], &rt1, &rt2, &c, &s);
                    for (int i = 0; i < 3; i++) {
                        float t = Z[i][l];
                        Z[i][l]     = c * t - s * Z[i][l - 1];
                        Z[i][l - 1] = s * t + c * Z[i][l - 1];
                    }
                    d[l - 1] = rt1; d[l] = rt2; e[l - 1] = 0.f;
                    l += 2;
                    if (l <= lend) continue;
                    break;
                }
                if (jtot == nmaxit) break;
                jtot++;
                float g = (d[l] - p) / (2.f * e[l - 1]);
                float r = slapy2_(g, 1.f);
                g = d[m2 - 1] - p + e[l - 1] / (g + copysignf(r, g));
                float s = 1.f, c = 1.f;
                p = 0.f;
                float csv[2], snv[2];
                for (int i = m2 - 1; i >= l; --i) {
                    float f = s * e[i - 1];
                    float b = c * e[i - 1];
                    slartg_(g, f, &c, &s, &r);
                    if (i != m2 - 1) e[i] = r;
                    g = d[i] - p;
                    r = (d[i - 1] - g) * s + 2.f * c * b;
                    p = s * r;
                    d[i] = g + p;
                    g = c * r - b;
                    csv[i - l] = c; snv[i - l] = -s;
                }
                int nrot = m2 - l;
                for (int j = nrot; j >= 1; --j) {
                    float C = csv[j - 1], S = snv[j - 1];
                    for (int i = 0; i < 3; i++) {
                        float t = Z[i][l - 1 + j];
                        Z[i][l - 1 + j] = C * t - S * Z[i][l - 2 + j];
                        Z[i][l - 2 + j] = S * t + C * Z[i][l - 2 + j];
                    }
                }
                d[l - 1] = d[l - 1] - p;
                e[l - 1] = g;
            }
        } else {
            for (;;) {
                if (++guard > 600) return;
                int m2 = lend;
                if (l != lend) {
                    for (int mm = l; mm >= lend + 1; --mm) {
                        float tst = e[mm - 2] * e[mm - 2];
                        if (tst <= (eps2 * fabsf(d[mm - 1])) * fabsf(d[mm - 2]) + safmin) { m2 = mm; break; }
                    }
                }
                if (m2 > lend) e[m2 - 2] = 0.f;
                float p = d[l - 1];
                if (m2 == l) {
                    d[l - 1] = p; l = l - 1;
                    if (l >= lend) continue;
                    break;
                }
                if (m2 == l - 1) {
                    float rt1, rt2, c, s;
                    slaev2_(d[l - 2], e[l - 2], d[l - 1], &rt1, &rt2, &c, &s);
                    for (int i = 0; i < 3; i++) {
                        float t = Z[i][l - 1];
                        Z[i][l - 1] = c * t - s * Z[i][l - 2];
                        Z[i][l - 2] = s * t + c * Z[i][l - 2];
                    }
                    d[l - 2] = rt1; d[l - 1] = rt2; e[l - 2] = 0.f;
                    l -= 2;
                    if (l >= lend) continue;
                    break;
                }
                if (jtot == nmaxit) break;
                jtot++;
                float g = (d[l - 2] - p) / (2.f * e[l - 2]);
                float r = slapy2_(g, 1.f);
                g = d[m2 - 1] - p + e[l - 2] / (g + copysignf(r, g));
                float s = 1.f, c = 1.f;
                p = 0.f;
                float csv[2], snv[2];
                for (int i = m2; i <= l - 1; ++i) {
                    float f = s * e[i - 1];
                    float b = c * e[i - 1];
                    slartg_(g, f, &c, &s, &r);
                    if (i != m2) e[i - 2] = r;
                    g = d[i - 1] - p;
                    r = (d[i] - g) * s + 2.f * c * b;
                    p = s * r;
                    d[i - 1] = g + p;
                    g = c * r - b;
                    csv[i - m2] = c; snv[i - m2] = s;
                }
                int nrot = l - m2;
                for (int j = 1; j <= nrot; ++j) {
                    float C = csv[j - 1], S = snv[j - 1];
                    for (int i = 0; i < 3; i++) {
                        float t = Z[i][m2 - 1 + j];
                        Z[i][m2 - 1 + j] = C * t - S * Z[i][m2 - 2 + j];
                        Z[i][m2 - 2 + j] = S * t + C * Z[i][m2 - 2 + j];
                    }
                }
                d[l - 1] -= p;
                e[l - 2] = g;
            }
        }
    }
    for (int ii = 2; ii <= n; ++ii) {
        int i = ii - 1, k = i;
        float p = d[i - 1];
        for (int j = ii; j <= n; ++j) {
            if (d[j - 1] < p) { k = j; p = d[j - 1]; }
        }
        if (k != i) {
            d[k - 1] = d[i - 1]; d[i - 1] = p;
            for (int r2 = 0; r2 < 3; r2++) {
                float t = Z[r2][i - 1]; Z[r2][i - 1] = Z[r2][k - 1]; Z[r2][k - 1] = t;
            }
        }
    }
}

__device__ void eig_normal3(const float xs[KNN], const float ys[KNN], const float zs[KNN],
                            float out[3]) {
    float mx = 0.f, my = 0.f, mz = 0.f;
#pragma unroll
    for (int s = 0; s < KNN; s++) { mx += xs[s]; my += ys[s]; mz += zs[s]; }
    mx /= 10.0f; my /= 10.0f; mz /= 10.0f;

    float c00 = 0.f, c10 = 0.f, c20 = 0.f, c11 = 0.f, c21 = 0.f, c22 = 0.f;
#pragma unroll
    for (int s = 0; s < KNN; s++) {
        float dx = xs[s] - mx, dy = ys[s] - my, dz = zs[s] - mz;
        c00 = fmaf(dx, dx, c00);
        c10 = fmaf(dy, dx, c10);
        c20 = fmaf(dz, dx, c20);
        c11 = fmaf(dy, dy, c11);
        c21 = fmaf(dz, dy, c21);
        c22 = fmaf(dz, dz, c22);
    }
    c00 /= 10.0f; c10 /= 10.0f; c20 /= 10.0f; c11 /= 10.0f; c21 /= 10.0f; c22 /= 10.0f;

    float alpha = c10, x2 = c20;
    float tau, v2, beta;
    float xnorm = fabsf(x2);
    if (xnorm == 0.f) { tau = 0.f; v2 = 0.f; beta = alpha; }
    else {
        beta = -copysignf(slapy2_(alpha, xnorm), alpha);
        tau = (beta - alpha) / beta;
        v2 = x2 / (alpha - beta);
    }
    float d[3], e[2];
    d[0] = c00;
    if (tau != 0.f) {
        float p0 = tau * (c11 + c21 * v2);
        float p1 = tau * (c21 + c22 * v2);
        float aw = -0.5f * tau * (p0 + p1 * v2);
        float w0 = p0 + aw;
        float w1 = p1 + aw * v2;
        d[1] = (c11 - w0) - w0;
        e[1] = (c21 - v2 * w0) - w1;
        d[2] = (c22 - v2 * w1) - w1 * v2;
        e[0] = beta;
    } else {
        d[1] = c11; d[2] = c22; e[0] = beta; e[1] = c21;
    }

    float Z[3][3] = {{1.f, 0.f, 0.f}, {0.f, 1.f, 0.f}, {0.f, 0.f, 1.f}};
    steqr3_(d, e, Z);

    float y0 = Z[0][0], y1 = Z[1][0], y2 = Z[2][0];
    if (tau != 0.f) {
        float t = tau * (y1 + v2 * y2);
        y1 = y1 - t;
        y2 = y2 - t * v2;
    }
    out[0] = y0; out[1] = y1; out[2] = y2;
}

__device__ __forceinline__ void merge_round(float* v, int off) {
    float t[KNN];
#pragma unroll
    for (int i = 0; i < KNN; i++) t[i] = fminf(v[i], __shfl_xor(v[KNN - 1 - i], off));
#define CE(a, b) { float hi = fmaxf(t[a], t[b]); float lo = fminf(t[a], t[b]); t[a] = hi; t[b] = lo; }
    CE(0, 8) CE(1, 9)
    CE(0, 4) CE(1, 5) CE(2, 6) CE(3, 7)
    CE(0, 2) CE(1, 3) CE(4, 6) CE(5, 7)
    CE(0, 1) CE(2, 3) CE(4, 5) CE(6, 7) CE(8, 9)
#undef CE
#pragma unroll
    for (int i = 0; i < KNN; i++) v[i] = t[i];
}

// ---------------- float4-LDS phase: 128 queries, dynamic shared -------------
// pts[j] = {x, y, z, w} with w staged once (same fmaf chain as the R1-R11
// tail -> identical bits). Pass 1/2: 1 ds_read_b128 + 3-fma key per
// candidate. Tail selects by the EXACT reference d2 formula (bitwise R1-R11).
__device__ void do_phase4(const float* __restrict__ src, int chunk, int tid,
                          float4* pts, unsigned short* spairs, int* scnt,
                          float nv[3]) {
    for (int j = tid; j < NPTS; j += 512) {
        float x = src[j], y = src[NPTS + j], z = src[2 * NPTS + j];
        float w = fmaf(z, z, fmaf(y, y, x * x));
        pts[j] = make_float4(x, y, z, w);
    }
    if (tid < 128) scnt[tid] = 0;
    __syncthreads();

    int part = tid & 15;          // 0..15
    int qg = tid >> 4;            // 0..31
    int ql0 = qg * 4;
    int q0 = chunk * 128 + ql0;

    float m2x[4], m2y[4], m2z[4];
#pragma unroll
    for (int c = 0; c < 4; c++) {
        float4 p = pts[q0 + c];
        m2x[c] = -2.f * p.x; m2y[c] = -2.f * p.y; m2z[c] = -2.f * p.z;
    }

    // ---- pass 1: med3 chain over 8-candidate group-min keys ----------------
    float v[4][KNN + 1];
#pragma unroll
    for (int c = 0; c < 4; c++) {
#pragma unroll
        for (int s = 0; s < KNN; s++) v[c][s] = INFINITY;
        v[c][KNN] = -INFINITY;
    }

#pragma unroll 2
    for (int g = 0; g < 32; g++) {
        int jb = part + 128 * g;
        float m[4] = {INFINITY, INFINITY, INFINITY, INFINITY};
#pragma unroll
        for (int u = 0; u < 8; u++) {
            float4 p = pts[jb + 16 * u];
#pragma unroll
            for (int c = 0; c < 4; c++) {
                float key = fmaf(m2z[c], p.z, fmaf(m2y[c], p.y, fmaf(m2x[c], p.x, p.w)));
                m[c] = fminf(m[c], key);
            }
        }
#pragma unroll
        for (int c = 0; c < 4; c++)
#pragma unroll
            for (int s = 0; s < KNN; s++) v[c][s] = med3f(m[c], v[c][s], v[c][s + 1]);
    }

    // ---- merge the 16 part-lists (4 xor rounds) -> tau ---------------------
    float tauS[4];
#pragma unroll
    for (int c = 0; c < 4; c++) {
        merge_round(v[c], 1);
        merge_round(v[c], 2);
        merge_round(v[c], 4);
        merge_round(v[c], 8);
        tauS[c] = v[c][0] + TAU_SLACK;
    }

    // ---- pass 2: collect idx with key <= tau+slack -------------------------
#pragma unroll 2
    for (int mm = 0; mm < 256; mm++) {
        int j = part + 16 * mm;
        float4 p = pts[j];
#pragma unroll
        for (int c = 0; c < 4; c++) {
            float key = fmaf(m2z[c], p.z, fmaf(m2y[c], p.y, fmaf(m2x[c], p.x, p.w)));
            if (key <= tauS[c]) {
                int ql = ql0 + c;
                int pos = atomicAdd(&scnt[ql], 1);
                if (pos < CAP) spairs[ql * CAP + pos] = (unsigned short)j;
            }
        }
    }
    __syncthreads();

    // ---- tail: exact top-10 by reference (d2, idx), waves 0-1 --------------
    if (tid < 128) {
        int ql = tid;
        int qi = chunk * 128 + ql;
        float4 q = pts[qi];
        float qw = q.w;
        int cnt = scnt[ql];

        float bd[KNN]; int bi_[KNN];
        if (cnt > CAP) {
            // overflow: exact full rescan (correctness net)
#pragma unroll
            for (int s = 0; s < KNN; s++) { bd[s] = 3.4e38f; bi_[s] = 0; }
            float worst = 3.4e38f;
            int wslot = 0;
            for (int j = 0; j < NPTS; j++) {
                float4 p = pts[j];
                float dot = fmaf(q.z, p.z, fmaf(q.y, p.y, q.x * p.x));
                float d2 = (qw + p.w) - 2.f * dot;
                if (d2 < worst) {
#pragma unroll
                    for (int s = 0; s < KNN; s++) { if (s == wslot) { bd[s] = d2; bi_[s] = j; } }
                    float wm = bd[0]; int ws = 0;
#pragma unroll
                    for (int s = 1; s < KNN; s++) { if (bd[s] > wm) { wm = bd[s]; ws = s; } }
                    worst = wm; wslot = ws;
                }
            }
        } else {
#pragma unroll
            for (int s = 0; s < KNN; s++) { bd[s] = 3.4e38f; bi_[s] = 0; }
            float worst = 3.4e38f;
            int wslot = 0;
            for (int t = 0; t < cnt; t++) {
                int j = spairs[ql * CAP + t];
                float4 p = pts[j];
                float dot = fmaf(q.z, p.z, fmaf(q.y, p.y, q.x * p.x));
                float d2 = (qw + p.w) - 2.f * dot;
                if (d2 < worst) {
#pragma unroll
                    for (int s = 0; s < KNN; s++) { if (s == wslot) { bd[s] = d2; bi_[s] = j; } }
                    float wm = bd[0]; int ws = 0;
#pragma unroll
                    for (int s = 1; s < KNN; s++) { if (bd[s] > wm) { wm = bd[s]; ws = s; } }
                    worst = wm; wslot = ws;
                }
            }
        }
        // sort by (d2, idx) ascending == jax.lax.top_k order
#pragma unroll
        for (int a = 0; a < KNN - 1; a++)
#pragma unroll
            for (int b2 = 0; b2 < KNN - 1 - a; b2++) {
                bool sw = (bd[b2] > bd[b2 + 1]) ||
                          (bd[b2] == bd[b2 + 1] && bi_[b2] > bi_[b2 + 1]);
                float d_lo = sw ? bd[b2 + 1] : bd[b2];
                float d_hi = sw ? bd[b2] : bd[b2 + 1];
                int   i_lo = sw ? bi_[b2 + 1] : bi_[b2];
                int   i_hi = sw ? bi_[b2] : bi_[b2 + 1];
                bd[b2] = d_lo; bd[b2 + 1] = d_hi; bi_[b2] = i_lo; bi_[b2 + 1] = i_hi;
            }
        float xs[KNN], ys[KNN], zs[KNN];
#pragma unroll
        for (int s = 0; s < KNN; s++) {
            float4 p = pts[bi_[s]];
            xs[s] = p.x; ys[s] = p.y; zs[s] = p.z;
        }
        eig_normal3(xs, ys, zs, nv);
    }
    __syncthreads();
}

// normals + last-block inline loss reduction. grid = 512 (2 blocks/CU).
__global__ __launch_bounds__(512, 4) void normals4_kernel(const float* __restrict__ pred,
                                                          const float* __restrict__ gt,
                                                          float* __restrict__ nrm,
                                                          int* __restrict__ done,
                                                          float* __restrict__ out) {
    extern __shared__ char dynlds[];
    float4* pts = (float4*)dynlds;
    unsigned short* spairs = (unsigned short*)(dynlds + NPTS * 16);
    int* scnt = (int*)(dynlds + NPTS * 16 + 128 * CAP * 2);
    __shared__ int is_last;
    __shared__ float wsum[8];

    int tid = threadIdx.x;
    int bid = blockIdx.x;
    int cloud = bid >> 8;
    int b = (bid >> 5) & 7;
    int chunk = bid & 31;

    const float* src = (cloud == 0 ? pred : gt) + (size_t)b * 3 * NPTS;
    float nv[3] = {0.f, 0.f, 0.f};
    do_phase4(src, chunk, tid, pts, spairs, scnt, nv);

    if (tid < 128) {
        int qg2 = chunk * 128 + tid;
        float* dst = nrm + ((size_t)cloud * 8 + b) * 3 * NPTS;
        dst[0 * NPTS + qg2] = nv[0];
        dst[1 * NPTS + qg2] = nv[1];
        dst[2 * NPTS + qg2] = nv[2];
    }
    __threadfence();                       // release nrm writes (device scope)
    __syncthreads();
    if (tid == 0) is_last = (atomicAdd(done, 1) == (int)gridDim.x - 1);
    __syncthreads();
    if (is_last) {
        __threadfence();                   // acquire before reading all nrm
        const float* a = nrm;
        const float* bb = nrm + NRM_N;
        float acc = 0.f;
        for (int i = tid; i < NRM_N; i += 512) {
            float dd = a[i] - bb[i];
            acc = fmaf(dd, dd, acc);
        }
#pragma unroll
        for (int off = 32; off > 0; off >>= 1) acc += __shfl_down(acc, off);
        int lane = tid & 63, wv = tid >> 6;
        if (lane == 0) wsum[wv] = acc;
        __syncthreads();
        if (tid == 0) {
            float t = 0.f;
#pragma unroll
            for (int i = 0; i < 8; i++) t += wsum[i];
            out[0] = t * (1.f / (float)NRM_N);   // single writer — no atomic
        }
    }
}

// ---------------- R11-verbatim static fallback (gate failure path) ----------
__device__ void do_phase_static(const float* __restrict__ src, int chunk, int tid,
                                float2* sxy, float* sz, unsigned short* spairs, int* scnt,
                                float nv[3]) {
    for (int j = tid; j < NPTS; j += 512) {
        float x = src[j], y = src[NPTS + j], z = src[2 * NPTS + j];
        sxy[j] = make_float2(x, y);
        sz[j] = z;
    }
    if (tid < 128) scnt[tid] = 0;
    __syncthreads();

    int part = tid & 15;
    int qg = tid >> 4;
    int ql0 = qg * 4;
    int q0 = chunk * 128 + ql0;

    float m2x[4], m2y[4], m2z[4];
#pragma unroll
    for (int c = 0; c < 4; c++) {
        float2 a = sxy[q0 + c];
        float z = sz[q0 + c];
        m2x[c] = -2.f * a.x; m2y[c] = -2.f * a.y; m2z[c] = -2.f * z;
    }

    float v[4][KNN + 1];
#pragma unroll
    for (int c = 0; c < 4; c++) {
#pragma unroll
        for (int s = 0; s < KNN; s++) v[c][s] = INFINITY;
        v[c][KNN] = -INFINITY;
    }

#pragma unroll 2
    for (int g = 0; g < 32; g++) {
        int jb = part + 128 * g;
        float m[4] = {INFINITY, INFINITY, INFINITY, INFINITY};
#pragma unroll
        for (int u = 0; u < 8; u++) {
            int j = jb + 16 * u;
            float2 a = sxy[j];
            float z = sz[j];
            float w = fmaf(z, z, fmaf(a.y, a.y, a.x * a.x));
#pragma unroll
            for (int c = 0; c < 4; c++) {
                float key = fmaf(m2z[c], z, fmaf(m2y[c], a.y, fmaf(m2x[c], a.x, w)));
                m[c] = fminf(m[c], key);
            }
        }
#pragma unroll
        for (int c = 0; c < 4; c++)
#pragma unroll
            for (int s = 0; s < KNN; s++) v[c][s] = med3f(m[c], v[c][s], v[c][s + 1]);
    }

    float tauS[4];
#pragma unroll
    for (int c = 0; c < 4; c++) {
        merge_round(v[c], 1);
        merge_round(v[c], 2);
        merge_round(v[c], 4);
        merge_round(v[c], 8);
        tauS[c] = v[c][0] + TAU_SLACK;
    }

#pragma unroll 2
    for (int mm = 0; mm < 256; mm++) {
        int j = part + 16 * mm;
        float2 a = sxy[j];
        float z = sz[j];
        float w = fmaf(z, z, fmaf(a.y, a.y, a.x * a.x));
#pragma unroll
        for (int c = 0; c < 4; c++) {
            float key = fmaf(m2z[c], z, fmaf(m2y[c], a.y, fmaf(m2x[c], a.x, w)));
            if (key <= tauS[c]) {
                int ql = ql0 + c;
                int pos = atomicAdd(&scnt[ql], 1);
                if (pos < CAP) spairs[ql * CAP + pos] = (unsigned short)j;
            }
        }
    }
    __syncthreads();

    if (tid < 128) {
        int ql = tid;
        int qi = chunk * 128 + ql;
        float2 qa = sxy[qi];
        float qzz = sz[qi];
        float qw = fmaf(qzz, qzz, fmaf(qa.y, qa.y, qa.x * qa.x));
        int cnt = scnt[ql];

        float bd[KNN]; int bi_[KNN];
#pragma unroll
        for (int s = 0; s < KNN; s++) { bd[s] = 3.4e38f; bi_[s] = 0; }
        float worst = 3.4e38f;
        int wslot = 0;
        if (cnt > CAP) {
            for (int j = 0; j < NPTS; j++) {
                float2 a = sxy[j];
                float z = sz[j];
                float w = fmaf(z, z, fmaf(a.y, a.y, a.x * a.x));
                float dot = fmaf(qzz, z, fmaf(qa.y, a.y, qa.x * a.x));
                float d2 = (qw + w) - 2.f * dot;
                if (d2 < worst) {
#pragma unroll
                    for (int s = 0; s < KNN; s++) { if (s == wslot) { bd[s] = d2; bi_[s] = j; } }
                    float wm = bd[0]; int ws = 0;
#pragma unroll
                    for (int s = 1; s < KNN; s++) { if (bd[s] > wm) { wm = bd[s]; ws = s; } }
                    worst = wm; wslot = ws;
                }
            }
        } else {
            for (int t = 0; t < cnt; t++) {
                int j = spairs[ql * CAP + t];
                float2 a = sxy[j];
                float z = sz[j];
                float w = fmaf(z, z, fmaf(a.y, a.y, a.x * a.x));
                float dot = fmaf(qzz, z, fmaf(qa.y, a.y, qa.x * a.x));
                float d2 = (qw + w) - 2.f * dot;
                if (d2 < worst) {
#pragma unroll
                    for (int s = 0; s < KNN; s++) { if (s == wslot) { bd[s] = d2; bi_[s] = j; } }
                    float wm = bd[0]; int ws = 0;
#pragma unroll
                    for (int s = 1; s < KNN; s++) { if (bd[s] > wm) { wm = bd[s]; ws = s; } }
                    worst = wm; wslot = ws;
                }
            }
        }
#pragma unroll
        for (int a = 0; a < KNN - 1; a++)
#pragma unroll
            for (int b2 = 0; b2 < KNN - 1 - a; b2++) {
                bool sw = (bd[b2] > bd[b2 + 1]) ||
                          (bd[b2] == bd[b2 + 1] && bi_[b2] > bi_[b2 + 1]);
                float d_lo = sw ? bd[b2 + 1] : bd[b2];
                float d_hi = sw ? bd[b2] : bd[b2 + 1];
                int   i_lo = sw ? bi_[b2 + 1] : bi_[b2];
                int   i_hi = sw ? bi_[b2] : bi_[b2 + 1];
                bd[b2] = d_lo; bd[b2 + 1] = d_hi; bi_[b2] = i_lo; bi_[b2 + 1] = i_hi;
            }
        float xs[KNN], ys[KNN], zs[KNN];
#pragma unroll
        for (int s = 0; s < KNN; s++) {
            int j = bi_[s];
            float2 a = sxy[j];
            xs[s] = a.x; ys[s] = a.y; zs[s] = sz[j];
        }
        eig_normal3(xs, ys, zs, nv);
    }
    __syncthreads();
}

__global__ __launch_bounds__(512, 4) void normals_kernel(const float* __restrict__ pred,
                                                         const float* __restrict__ gt,
                                                         float* __restrict__ nrm,
                                                         float* __restrict__ out) {
    __shared__ float2 sxy[NPTS];
    __shared__ float  sz[NPTS];
    __shared__ unsigned short spairs[128 * CAP];
    __shared__ int scnt[128];

    int tid = threadIdx.x;
    int bid = blockIdx.x;
    if (bid == 0 && tid == 0) out[0] = 0.f;
    int cloud = bid >> 8;
    int b = (bid >> 5) & 7;
    int chunk = bid & 31;

    const float* src = (cloud == 0 ? pred : gt) + (size_t)b * 3 * NPTS;
    float nv[3] = {0.f, 0.f, 0.f};
    do_phase_static(src, chunk, tid, sxy, sz, spairs, scnt, nv);

    if (tid < 128) {
        int qg2 = chunk * 128 + tid;
        float* dst = nrm + ((size_t)cloud * 8 + b) * 3 * NPTS;
        dst[0 * NPTS + qg2] = nv[0];
        dst[1 * NPTS + qg2] = nv[1];
        dst[2 * NPTS + qg2] = nv[2];
    }
}

__global__ __launch_bounds__(256) void loss_kernel(const float* __restrict__ nrm,
                                                   float* __restrict__ out) {
    const int n = NRM_N;
    const float* a = nrm;
    const float* b = nrm + n;
    float acc = 0.f;
    for (int i = blockIdx.x * 256 + threadIdx.x; i < n; i += gridDim.x * 256) {
        float dd = a[i] - b[i];
        acc = fmaf(dd, dd, acc);
    }
#pragma unroll
    for (int off = 32; off > 0; off >>= 1) acc += __shfl_down(acc, off);
    __shared__ float wsum[4];
    int lane = threadIdx.x & 63, wv = threadIdx.x >> 6;
    if (lane == 0) wsum[wv] = acc;
    __syncthreads();
    if (threadIdx.x == 0) {
        float t = wsum[0] + wsum[1] + wsum[2] + wsum[3];
        atomicAdd(out, t * (1.f / (float)n));
    }
}

extern "C" void kernel_launch(void* const* d_in, const int* in_sizes, int n_in,
                              void* d_out, int out_size, void* d_ws, size_t ws_size,
                              hipStream_t stream) {
    (void)in_sizes; (void)n_in; (void)out_size;
    const float* pred = (const float*)d_in[0];
    const float* gt   = (const float*)d_in[1];
    float* out = (float*)d_out;

    size_t need = (size_t)2 * NRM_N * sizeof(float) + 64;   // nrm + counter
    float* nrm = (float*)d_ws;
    int* done = (int*)((char*)d_ws + (size_t)2 * NRM_N * sizeof(float));

    // gate: can this device take 78336 B of dynamic LDS per workgroup?
    int dev = 0;
    hipGetDevice(&dev);
    int maxShm = 0;
    hipDeviceGetAttribute(&maxShm, hipDeviceAttributeMaxSharedMemoryPerBlock, dev);
    hipError_t eAttr = hipFuncSetAttribute(
        reinterpret_cast<const void*>(normals4_kernel),
        hipFuncAttributeMaxDynamicSharedMemorySize, DYN_BYTES);
    bool use4 = (ws_size >= need) && ((maxShm >= DYN_BYTES) || (eAttr == hipSuccess));

    if (use4) {
        hipMemsetAsync(done, 0, sizeof(int), stream);
        hipLaunchKernelGGL(normals4_kernel, dim3(512), dim3(512), DYN_BYTES, stream,
                           pred, gt, nrm, done, out);
    } else if (ws_size >= need) {
        hipLaunchKernelGGL(normals_kernel, dim3(512), dim3(512), 0, stream,
                           pred, gt, nrm, out);
        hipLaunchKernelGGL(loss_kernel, dim3(96), dim3(256), 0, stream, nrm, out);
    } else {
        // no workspace: R11 static path writing into a small stack-free fallback
        // (should not happen; harness provides ws)
        hipMemsetAsync(d_out, 0, sizeof(float), stream);
        hipLaunchKernelGGL(normals_kernel, dim3(512), dim3(512), 0, stream,
                           pred, gt, (float*)d_ws, out);
        hipLaunchKernelGGL(loss_kernel, dim3(96), dim3(256), 0, stream, (float*)d_ws, out);
    }
}

// Round 13
// 168.862 us; speedup vs baseline: 2.7467x; 2.7467x over previous
//
#include <hip/hip_runtime.h>
#include <math.h>

#define NPTS 4096
#define KNN 10
#define CAP 48          // group-8 bound is <=80; overflow -> exact full rescan
#define TAU_SLACK 1e-4f // covers key-vs-d2 rounding skew (~2e-6 abs)
#define NRM_N (8 * 3 * NPTS)
#define DYN_BYTES (NPTS * 16 + 128 * CAP * 2 + 512)   // 78336

__device__ __forceinline__ float med3f(float a, float b, float c) {
    return __builtin_amdgcn_fmed3f(a, b, c);
}

// ---------------- LAPACK building blocks (f32, faithful to netlib) ----------
// Verified bit-exact vs numpy/LAPACK in R1-R12 (absmax 0.0). DO NOT TOUCH.

__device__ __forceinline__ float slapy2_(float x, float y) {
    float ax = fabsf(x), ay = fabsf(y);
    float w = fmaxf(ax, ay), z = fminf(ax, ay);
    if (z == 0.f) return w;
    float t = z / w;
    return w * sqrtf(1.f + t * t);
}

__device__ __forceinline__ void slartg_(float f, float g, float* c, float* s, float* r) {
    if (g == 0.f) { *c = 1.f; *s = 0.f; *r = f; }
    else if (f == 0.f) { *c = 0.f; *s = copysignf(1.f, g); *r = fabsf(g); }
    else {
        float f1 = fabsf(f);
        float d = sqrtf(f * f + g * g);
        float rr = copysignf(d, f);
        *c = f1 / d;
        *s = g / rr;
        *r = rr;
    }
}

__device__ void slaev2_(float a, float b, float c,
                        float* rt1, float* rt2, float* cs1, float* sn1) {
    float sm = a + c;
    float df = a - c;
    float adf = fabsf(df);
    float tb = b + b;
    float ab = fabsf(tb);
    float acmx, acmn;
    if (fabsf(a) > fabsf(c)) { acmx = a; acmn = c; } else { acmx = c; acmn = a; }
    float rt;
    if (adf > ab)      { float t = ab / adf; rt = adf * sqrtf(1.f + t * t); }
    else if (adf < ab) { float t = adf / ab; rt = ab * sqrtf(1.f + t * t); }
    else               { rt = ab * sqrtf(2.f); }
    int sgn1;
    if (sm < 0.f) {
        *rt1 = 0.5f * (sm - rt); sgn1 = -1;
        *rt2 = (acmx / *rt1) * acmn - (b / *rt1) * b;
    } else if (sm > 0.f) {
        *rt1 = 0.5f * (sm + rt); sgn1 = 1;
        *rt2 = (acmx / *rt1) * acmn - (b / *rt1) * b;
    } else {
        *rt1 = 0.5f * rt; *rt2 = -0.5f * rt; sgn1 = 1;
    }
    int sgn2;
    float cs;
    if (df >= 0.f) { cs = df + rt; sgn2 = 1; } else { cs = df - rt; sgn2 = -1; }
    float acs = fabsf(cs);
    if (acs > ab) {
        float ct = -tb / cs;
        *sn1 = 1.f / sqrtf(1.f + ct * ct);
        *cs1 = ct * (*sn1);
    } else {
        if (ab == 0.f) { *cs1 = 1.f; *sn1 = 0.f; }
        else {
            float tn = -cs / tb;
            *cs1 = 1.f / sqrtf(1.f + tn * tn);
            *sn1 = tn * (*cs1);
        }
    }
    if (sgn1 == sgn2) { float tn = *cs1; *cs1 = -(*sn1); *sn1 = tn; }
}

__device__ void steqr3_(float* d, float* e, float Z[3][3]) {
    const float eps    = 5.9604644775390625e-8f;  // 2^-24
    const float eps2   = eps * eps;
    const float safmin = 1.17549435e-38f;
    const int n = 3, nm1 = 2;
    const int nmaxit = 90;
    int jtot = 0, l1 = 1;
    int guard = 0;

    while (l1 <= n) {
        if (++guard > 600) break;
        if (l1 > 1) e[l1 - 2] = 0.f;
        int m = n;
        if (l1 <= nm1) {
            for (int mm = l1; mm <= nm1; ++mm) {
                float tst = fabsf(e[mm - 1]);
                if (tst == 0.f) { m = mm; break; }
                if (tst <= (sqrtf(fabsf(d[mm - 1])) * sqrtf(fabsf(d[mm]))) * eps) {
                    e[mm - 1] = 0.f; m = mm; break;
                }
            }
        }
        int l = l1, lsv = l1, lend = m, lendsv = m;
        l1 = m + 1;
        if (lend == l) continue;
        float anorm = 0.f;
        for (int i = l; i <= lend; i++) anorm = fmaxf(anorm, fabsf(d[i - 1]));
        for (int i = l; i <= lend - 1; i++) anorm = fmaxf(anorm, fabsf(e[i - 1]));
        if (anorm == 0.f) continue;
        if (fabsf(d[lend - 1]) < fabsf(d[l - 1])) { lend = lsv; l = lendsv; }

        if (lend > l) {
            for (;;) {
                if (++guard > 600) return;
                int m2 = lend;
                if (l != lend) {
                    for (int mm = l; mm <= lend - 1; ++mm) {
                        float tst = e[mm - 1] * e[mm - 1];
                        if (tst <= (eps2 * fabsf(d[mm - 1])) * fabsf(d[mm]) + safmin) { m2 = mm; break; }
                    }
                }
                if (m2 < lend) e[m2 - 1] = 0.f;
                float p = d[l - 1];
                if (m2 == l) {
                    d[l - 1] = p; l = l + 1;
                    if (l <= lend) continue;
                    break;
                }
                if (m2 == l + 1) {
                    float rt1, rt2, c, s;
                    slaev2_(d[l - 1], e[l - 1], d[l], &rt1, &rt2, &c, &s);
                    for (int i = 0; i < 3; i++) {
                        float t = Z[i][l];
                        Z[i][l]     = c * t - s * Z[i][l - 1];
                        Z[i][l - 1] = s * t + c * Z[i][l - 1];
                    }
                    d[l - 1] = rt1; d[l] = rt2; e[l - 1] = 0.f;
                    l += 2;
                    if (l <= lend) continue;
                    break;
                }
                if (jtot == nmaxit) break;
                jtot++;
                float g = (d[l] - p) / (2.f * e[l - 1]);
                float r = slapy2_(g, 1.f);
                g = d[m2 - 1] - p + e[l - 1] / (g + copysignf(r, g));
                float s = 1.f, c = 1.f;
                p = 0.f;
                float csv[2], snv[2];
                for (int i = m2 - 1; i >= l; --i) {
                    float f = s * e[i - 1];
                    float b = c * e[i - 1];
                    slartg_(g, f, &c, &s, &r);
                    if (i != m2 - 1) e[i] = r;
                    g = d[i] - p;
                    r = (d[i - 1] - g) * s + 2.f * c * b;
                    p = s * r;
                    d[i] = g + p;
                    g = c * r - b;
                    csv[i - l] = c; snv[i - l] = -s;
                }
                int nrot = m2 - l;
                for (int j = nrot; j >= 1; --j) {
                    float C = csv[j - 1], S = snv[j - 1];
                    for (int i = 0; i < 3; i++) {
                        float t = Z[i][l - 1 + j];
                        Z[i][l - 1 + j] = C * t - S * Z[i][l - 2 + j];
                        Z[i][l - 2 + j] = S * t + C * Z[i][l - 2 + j];
                    }
                }
                d[l - 1] = d[l - 1] - p;
                e[l - 1] = g;
            }
        } else {
            for (;;) {
                if (++guard > 600) return;
                int m2 = lend;
                if (l != lend) {
                    for (int mm = l; mm >= lend + 1; --mm) {
                        float tst = e[mm - 2] * e[mm - 2];
                        if (tst <= (eps2 * fabsf(d[mm - 1])) * fabsf(d[mm - 2]) + safmin) { m2 = mm; break; }
                    }
                }
                if (m2 > lend) e[m2 - 2] = 0.f;
                float p = d[l - 1];
                if (m2 == l) {
                    d[l - 1] = p; l = l - 1;
                    if (l >= lend) continue;
                    break;
                }
                if (m2 == l - 1) {
                    float rt1, rt2, c, s;
                    slaev2_(d[l - 2], e[l - 2], d[l - 1], &rt1, &rt2, &c, &s);
                    for (int i = 0; i < 3; i++) {
                        float t = Z[i][l - 1];
                        Z[i][l - 1] = c * t - s * Z[i][l - 2];
                        Z[i][l - 2] = s * t + c * Z[i][l - 2];
                    }
                    d[l - 2] = rt1; d[l - 1] = rt2; e[l - 2] = 0.f;
                    l -= 2;
                    if (l >= lend) continue;
                    break;
                }
                if (jtot == nmaxit) break;
                jtot++;
                float g = (d[l - 2] - p) / (2.f * e[l - 2]);
                float r = slapy2_(g, 1.f);
                g = d[m2 - 1] - p + e[l - 2] / (g + copysignf(r, g));
                float s = 1.f, c = 1.f;
                p = 0.f;
                float csv[2], snv[2];
                for (int i = m2; i <= l - 1; ++i) {
                    float f = s * e[i - 1];
                    float b = c * e[i - 1];
                    slartg_(g, f, &c, &s, &r);
                    if (i != m2) e[i - 2] = r;
                    g = d[i - 1] - p;
                    r = (d[i] - g) * s + 2.f * c * b;
                    p = s * r;
                    d[i - 1] = g + p;
                    g = c * r - b;
                    csv[i - m2] = c; snv[i - m2] = s;
                }
                int nrot = l - m2;
                for (int j = 1; j <= nrot; ++j) {
                    float C = csv[j - 1], S = snv[j - 1];
                    for (int i = 0; i < 3; i++) {
                        float t = Z[i][m2 - 1 + j];
                        Z[i][m2 - 1 + j] = C * t - S * Z[i][m2 - 2 + j];
                        Z[i][m2 - 2 + j] = S * t + C * Z[i][m2 - 2 + j];
                    }
                }
                d[l - 1] -= p;
                e[l - 2] = g;
            }
        }
    }
    for (int ii = 2; ii <= n; ++ii) {
        int i = ii - 1, k = i;
        float p = d[i - 1];
        for (int j = ii; j <= n; ++j) {
            if (d[j - 1] < p) { k = j; p = d[j - 1]; }
        }
        if (k != i) {
            d[k - 1] = d[i - 1]; d[i - 1] = p;
            for (int r2 = 0; r2 < 3; r2++) {
                float t = Z[r2][i - 1]; Z[r2][i - 1] = Z[r2][k - 1]; Z[r2][k - 1] = t;
            }
        }
    }
}

__device__ void eig_normal3(const float xs[KNN], const float ys[KNN], const float zs[KNN],
                            float out[3]) {
    float mx = 0.f, my = 0.f, mz = 0.f;
#pragma unroll
    for (int s = 0; s < KNN; s++) { mx += xs[s]; my += ys[s]; mz += zs[s]; }
    mx /= 10.0f; my /= 10.0f; mz /= 10.0f;

    float c00 = 0.f, c10 = 0.f, c20 = 0.f, c11 = 0.f, c21 = 0.f, c22 = 0.f;
#pragma unroll
    for (int s = 0; s < KNN; s++) {
        float dx = xs[s] - mx, dy = ys[s] - my, dz = zs[s] - mz;
        c00 = fmaf(dx, dx, c00);
        c10 = fmaf(dy, dx, c10);
        c20 = fmaf(dz, dx, c20);
        c11 = fmaf(dy, dy, c11);
        c21 = fmaf(dz, dy, c21);
        c22 = fmaf(dz, dz, c22);
    }
    c00 /= 10.0f; c10 /= 10.0f; c20 /= 10.0f; c11 /= 10.0f; c21 /= 10.0f; c22 /= 10.0f;

    float alpha = c10, x2 = c20;
    float tau, v2, beta;
    float xnorm = fabsf(x2);
    if (xnorm == 0.f) { tau = 0.f; v2 = 0.f; beta = alpha; }
    else {
        beta = -copysignf(slapy2_(alpha, xnorm), alpha);
        tau = (beta - alpha) / beta;
        v2 = x2 / (alpha - beta);
    }
    float d[3], e[2];
    d[0] = c00;
    if (tau != 0.f) {
        float p0 = tau * (c11 + c21 * v2);
        float p1 = tau * (c21 + c22 * v2);
        float aw = -0.5f * tau * (p0 + p1 * v2);
        float w0 = p0 + aw;
        float w1 = p1 + aw * v2;
        d[1] = (c11 - w0) - w0;
        e[1] = (c21 - v2 * w0) - w1;
        d[2] = (c22 - v2 * w1) - w1 * v2;
        e[0] = beta;
    } else {
        d[1] = c11; d[2] = c22; e[0] = beta; e[1] = c21;
    }

    float Z[3][3] = {{1.f, 0.f, 0.f}, {0.f, 1.f, 0.f}, {0.f, 0.f, 1.f}};
    steqr3_(d, e, Z);

    float y0 = Z[0][0], y1 = Z[1][0], y2 = Z[2][0];
    if (tau != 0.f) {
        float t = tau * (y1 + v2 * y2);
        y1 = y1 - t;
        y2 = y2 - t * v2;
    }
    out[0] = y0; out[1] = y1; out[2] = y2;
}

__device__ __forceinline__ void merge_round(float* v, int off) {
    float t[KNN];
#pragma unroll
    for (int i = 0; i < KNN; i++) t[i] = fminf(v[i], __shfl_xor(v[KNN - 1 - i], off));
#define CE(a, b) { float hi = fmaxf(t[a], t[b]); float lo = fminf(t[a], t[b]); t[a] = hi; t[b] = lo; }
    CE(0, 8) CE(1, 9)
    CE(0, 4) CE(1, 5) CE(2, 6) CE(3, 7)
    CE(0, 2) CE(1, 3) CE(4, 6) CE(5, 7)
    CE(0, 1) CE(2, 3) CE(4, 5) CE(6, 7) CE(8, 9)
#undef CE
#pragma unroll
    for (int i = 0; i < KNN; i++) v[i] = t[i];
}

// ---------------- float4-LDS phase: 128 queries, dynamic shared -------------
// pts[j] = {x, y, z, w} with w staged once (same fmaf chain as the tail ->
// identical bits). Pass 1/2: 1 ds_read_b128 + 3-fma key per candidate.
// Tail selects by the EXACT reference d2 formula (bitwise R1-R12 output).
// NO device-scope fences anywhere (R12 lesson: per-block __threadfence on
// 8 non-coherent XCD L2s = L2 writeback per block = 3x slowdown; kernel
// boundaries provide coherence for free).
__device__ void do_phase4(const float* __restrict__ src, int chunk, int tid,
                          float4* pts, unsigned short* spairs, int* scnt,
                          float nv[3]) {
    for (int j = tid; j < NPTS; j += 512) {
        float x = src[j], y = src[NPTS + j], z = src[2 * NPTS + j];
        float w = fmaf(z, z, fmaf(y, y, x * x));
        pts[j] = make_float4(x, y, z, w);
    }
    if (tid < 128) scnt[tid] = 0;
    __syncthreads();

    int part = tid & 15;          // 0..15
    int qg = tid >> 4;            // 0..31
    int ql0 = qg * 4;
    int q0 = chunk * 128 + ql0;

    float m2x[4], m2y[4], m2z[4];
#pragma unroll
    for (int c = 0; c < 4; c++) {
        float4 p = pts[q0 + c];
        m2x[c] = -2.f * p.x; m2y[c] = -2.f * p.y; m2z[c] = -2.f * p.z;
    }

    // ---- pass 1: med3 chain over 8-candidate group-min keys ----------------
    float v[4][KNN + 1];
#pragma unroll
    for (int c = 0; c < 4; c++) {
#pragma unroll
        for (int s = 0; s < KNN; s++) v[c][s] = INFINITY;
        v[c][KNN] = -INFINITY;
    }

#pragma unroll 2
    for (int g = 0; g < 32; g++) {
        int jb = part + 128 * g;
        float m[4] = {INFINITY, INFINITY, INFINITY, INFINITY};
#pragma unroll
        for (int u = 0; u < 8; u++) {
            float4 p = pts[jb + 16 * u];
#pragma unroll
            for (int c = 0; c < 4; c++) {
                float key = fmaf(m2z[c], p.z, fmaf(m2y[c], p.y, fmaf(m2x[c], p.x, p.w)));
                m[c] = fminf(m[c], key);
            }
        }
#pragma unroll
        for (int c = 0; c < 4; c++)
#pragma unroll
            for (int s = 0; s < KNN; s++) v[c][s] = med3f(m[c], v[c][s], v[c][s + 1]);
    }

    // ---- merge the 16 part-lists (4 xor rounds) -> tau ---------------------
    float tauS[4];
#pragma unroll
    for (int c = 0; c < 4; c++) {
        merge_round(v[c], 1);
        merge_round(v[c], 2);
        merge_round(v[c], 4);
        merge_round(v[c], 8);
        tauS[c] = v[c][0] + TAU_SLACK;
    }

    // ---- pass 2: collect idx with key <= tau+slack -------------------------
#pragma unroll 2
    for (int mm = 0; mm < 256; mm++) {
        int j = part + 16 * mm;
        float4 p = pts[j];
#pragma unroll
        for (int c = 0; c < 4; c++) {
            float key = fmaf(m2z[c], p.z, fmaf(m2y[c], p.y, fmaf(m2x[c], p.x, p.w)));
            if (key <= tauS[c]) {
                int ql = ql0 + c;
                int pos = atomicAdd(&scnt[ql], 1);
                if (pos < CAP) spairs[ql * CAP + pos] = (unsigned short)j;
            }
        }
    }
    __syncthreads();

    // ---- tail: exact top-10 by reference (d2, idx), waves 0-1 --------------
    if (tid < 128) {
        int ql = tid;
        int qi = chunk * 128 + ql;
        float4 q = pts[qi];
        float qw = q.w;
        int cnt = scnt[ql];

        float bd[KNN]; int bi_[KNN];
#pragma unroll
        for (int s = 0; s < KNN; s++) { bd[s] = 3.4e38f; bi_[s] = 0; }
        float worst = 3.4e38f;
        int wslot = 0;
        if (cnt > CAP) {
            // overflow: exact full rescan (correctness net)
            for (int j = 0; j < NPTS; j++) {
                float4 p = pts[j];
                float dot = fmaf(q.z, p.z, fmaf(q.y, p.y, q.x * p.x));
                float d2 = (qw + p.w) - 2.f * dot;
                if (d2 < worst) {
#pragma unroll
                    for (int s = 0; s < KNN; s++) { if (s == wslot) { bd[s] = d2; bi_[s] = j; } }
                    float wm = bd[0]; int ws = 0;
#pragma unroll
                    for (int s = 1; s < KNN; s++) { if (bd[s] > wm) { wm = bd[s]; ws = s; } }
                    worst = wm; wslot = ws;
                }
            }
        } else {
            for (int t = 0; t < cnt; t++) {
                int j = spairs[ql * CAP + t];
                float4 p = pts[j];
                float dot = fmaf(q.z, p.z, fmaf(q.y, p.y, q.x * p.x));
                float d2 = (qw + p.w) - 2.f * dot;
                if (d2 < worst) {
#pragma unroll
                    for (int s = 0; s < KNN; s++) { if (s == wslot) { bd[s] = d2; bi_[s] = j; } }
                    float wm = bd[0]; int ws = 0;
#pragma unroll
                    for (int s = 1; s < KNN; s++) { if (bd[s] > wm) { wm = bd[s]; ws = s; } }
                    worst = wm; wslot = ws;
                }
            }
        }
        // sort by (d2, idx) ascending == jax.lax.top_k order
#pragma unroll
        for (int a = 0; a < KNN - 1; a++)
#pragma unroll
            for (int b2 = 0; b2 < KNN - 1 - a; b2++) {
                bool sw = (bd[b2] > bd[b2 + 1]) ||
                          (bd[b2] == bd[b2 + 1] && bi_[b2] > bi_[b2 + 1]);
                float d_lo = sw ? bd[b2 + 1] : bd[b2];
                float d_hi = sw ? bd[b2] : bd[b2 + 1];
                int   i_lo = sw ? bi_[b2 + 1] : bi_[b2];
                int   i_hi = sw ? bi_[b2] : bi_[b2 + 1];
                bd[b2] = d_lo; bd[b2 + 1] = d_hi; bi_[b2] = i_lo; bi_[b2 + 1] = i_hi;
            }
        float xs[KNN], ys[KNN], zs[KNN];
#pragma unroll
        for (int s = 0; s < KNN; s++) {
            float4 p = pts[bi_[s]];
            xs[s] = p.x; ys[s] = p.y; zs[s] = p.z;
        }
        eig_normal3(xs, ys, zs, nv);
    }
    __syncthreads();
}

// normals only — loss is a separate kernel (stream order = free coherence).
__global__ __launch_bounds__(512, 4) void normals4_kernel(const float* __restrict__ pred,
                                                          const float* __restrict__ gt,
                                                          float* __restrict__ nrm,
                                                          float* __restrict__ out) {
    extern __shared__ char dynlds[];
    float4* pts = (float4*)dynlds;
    unsigned short* spairs = (unsigned short*)(dynlds + NPTS * 16);
    int* scnt = (int*)(dynlds + NPTS * 16 + 128 * CAP * 2);

    int tid = threadIdx.x;
    int bid = blockIdx.x;
    if (bid == 0 && tid == 0) out[0] = 0.f;   // zero for loss's atomicAdd
    int cloud = bid >> 8;
    int b = (bid >> 5) & 7;
    int chunk = bid & 31;

    const float* src = (cloud == 0 ? pred : gt) + (size_t)b * 3 * NPTS;
    float nv[3] = {0.f, 0.f, 0.f};
    do_phase4(src, chunk, tid, pts, spairs, scnt, nv);

    if (tid < 128) {
        int qg2 = chunk * 128 + tid;
        float* dst = nrm + ((size_t)cloud * 8 + b) * 3 * NPTS;
        dst[0 * NPTS + qg2] = nv[0];
        dst[1 * NPTS + qg2] = nv[1];
        dst[2 * NPTS + qg2] = nv[2];
    }
}

// ---------------- R11-verbatim static fallback (gate failure path) ----------
__device__ void do_phase_static(const float* __restrict__ src, int chunk, int tid,
                                float2* sxy, float* sz, unsigned short* spairs, int* scnt,
                                float nv[3]) {
    for (int j = tid; j < NPTS; j += 512) {
        float x = src[j], y = src[NPTS + j], z = src[2 * NPTS + j];
        sxy[j] = make_float2(x, y);
        sz[j] = z;
    }
    if (tid < 128) scnt[tid] = 0;
    __syncthreads();

    int part = tid & 15;
    int qg = tid >> 4;
    int ql0 = qg * 4;
    int q0 = chunk * 128 + ql0;

    float m2x[4], m2y[4], m2z[4];
#pragma unroll
    for (int c = 0; c < 4; c++) {
        float2 a = sxy[q0 + c];
        float z = sz[q0 + c];
        m2x[c] = -2.f * a.x; m2y[c] = -2.f * a.y; m2z[c] = -2.f * z;
    }

    float v[4][KNN + 1];
#pragma unroll
    for (int c = 0; c < 4; c++) {
#pragma unroll
        for (int s = 0; s < KNN; s++) v[c][s] = INFINITY;
        v[c][KNN] = -INFINITY;
    }

#pragma unroll 2
    for (int g = 0; g < 32; g++) {
        int jb = part + 128 * g;
        float m[4] = {INFINITY, INFINITY, INFINITY, INFINITY};
#pragma unroll
        for (int u = 0; u < 8; u++) {
            int j = jb + 16 * u;
            float2 a = sxy[j];
            float z = sz[j];
            float w = fmaf(z, z, fmaf(a.y, a.y, a.x * a.x));
#pragma unroll
            for (int c = 0; c < 4; c++) {
                float key = fmaf(m2z[c], z, fmaf(m2y[c], a.y, fmaf(m2x[c], a.x, w)));
                m[c] = fminf(m[c], key);
            }
        }
#pragma unroll
        for (int c = 0; c < 4; c++)
#pragma unroll
            for (int s = 0; s < KNN; s++) v[c][s] = med3f(m[c], v[c][s], v[c][s + 1]);
    }

    float tauS[4];
#pragma unroll
    for (int c = 0; c < 4; c++) {
        merge_round(v[c], 1);
        merge_round(v[c], 2);
        merge_round(v[c], 4);
        merge_round(v[c], 8);
        tauS[c] = v[c][0] + TAU_SLACK;
    }

#pragma unroll 2
    for (int mm = 0; mm < 256; mm++) {
        int j = part + 16 * mm;
        float2 a = sxy[j];
        float z = sz[j];
        float w = fmaf(z, z, fmaf(a.y, a.y, a.x * a.x));
#pragma unroll
        for (int c = 0; c < 4; c++) {
            float key = fmaf(m2z[c], z, fmaf(m2y[c], a.y, fmaf(m2x[c], a.x, w)));
            if (key <= tauS[c]) {
                int ql = ql0 + c;
                int pos = atomicAdd(&scnt[ql], 1);
                if (pos < CAP) spairs[ql * CAP + pos] = (unsigned short)j;
            }
        }
    }
    __syncthreads();

    if (tid < 128) {
        int ql = tid;
        int qi = chunk * 128 + ql;
        float2 qa = sxy[qi];
        float qzz = sz[qi];
        float qw = fmaf(qzz, qzz, fmaf(qa.y, qa.y, qa.x * qa.x));
        int cnt = scnt[ql];

        float bd[KNN]; int bi_[KNN];
#pragma unroll
        for (int s = 0; s < KNN; s++) { bd[s] = 3.4e38f; bi_[s] = 0; }
        float worst = 3.4e38f;
        int wslot = 0;
        if (cnt > CAP) {
            for (int j = 0; j < NPTS; j++) {
                float2 a = sxy[j];
                float z = sz[j];
                float w = fmaf(z, z, fmaf(a.y, a.y, a.x * a.x));
                float dot = fmaf(qzz, z, fmaf(qa.y, a.y, qa.x * a.x));
                float d2 = (qw + w) - 2.f * dot;
                if (d2 < worst) {
#pragma unroll
                    for (int s = 0; s < KNN; s++) { if (s == wslot) { bd[s] = d2; bi_[s] = j; } }
                    float wm = bd[0]; int ws = 0;
#pragma unroll
                    for (int s = 1; s < KNN; s++) { if (bd[s] > wm) { wm = bd[s]; ws = s; } }
                    worst = wm; wslot = ws;
                }
            }
        } else {
            for (int t = 0; t < cnt; t++) {
                int j = spairs[ql * CAP + t];
                float2 a = sxy[j];
                float z = sz[j];
                float w = fmaf(z, z, fmaf(a.y, a.y, a.x * a.x));
                float dot = fmaf(qzz, z, fmaf(qa.y, a.y, qa.x * a.x));
                float d2 = (qw + w) - 2.f * dot;
                if (d2 < worst) {
#pragma unroll
                    for (int s = 0; s < KNN; s++) { if (s == wslot) { bd[s] = d2; bi_[s] = j; } }
                    float wm = bd[0]; int ws = 0;
#pragma unroll
                    for (int s = 1; s < KNN; s++) { if (bd[s] > wm) { wm = bd[s]; ws = s; } }
                    worst = wm; wslot = ws;
                }
            }
        }
#pragma unroll
        for (int a = 0; a < KNN - 1; a++)
#pragma unroll
            for (int b2 = 0; b2 < KNN - 1 - a; b2++) {
                bool sw = (bd[b2] > bd[b2 + 1]) ||
                          (bd[b2] == bd[b2 + 1] && bi_[b2] > bi_[b2 + 1]);
                float d_lo = sw ? bd[b2 + 1] : bd[b2];
                float d_hi = sw ? bd[b2] : bd[b2 + 1];
                int   i_lo = sw ? bi_[b2 + 1] : bi_[b2];
                int   i_hi = sw ? bi_[b2] : bi_[b2 + 1];
                bd[b2] = d_lo; bd[b2 + 1] = d_hi; bi_[b2] = i_lo; bi_[b2 + 1] = i_hi;
            }
        float xs[KNN], ys[KNN], zs[KNN];
#pragma unroll
        for (int s = 0; s < KNN; s++) {
            int j = bi_[s];
            float2 a = sxy[j];
            xs[s] = a.x; ys[s] = a.y; zs[s] = sz[j];
        }
        eig_normal3(xs, ys, zs, nv);
    }
    __syncthreads();
}

__global__ __launch_bounds__(512, 4) void normals_kernel(const float* __restrict__ pred,
                                                         const float* __restrict__ gt,
                                                         float* __restrict__ nrm,
                                                         float* __restrict__ out) {
    __shared__ float2 sxy[NPTS];
    __shared__ float  sz[NPTS];
    __shared__ unsigned short spairs[128 * CAP];
    __shared__ int scnt[128];

    int tid = threadIdx.x;
    int bid = blockIdx.x;
    if (bid == 0 && tid == 0) out[0] = 0.f;
    int cloud = bid >> 8;
    int b = (bid >> 5) & 7;
    int chunk = bid & 31;

    const float* src = (cloud == 0 ? pred : gt) + (size_t)b * 3 * NPTS;
    float nv[3] = {0.f, 0.f, 0.f};
    do_phase_static(src, chunk, tid, sxy, sz, spairs, scnt, nv);

    if (tid < 128) {
        int qg2 = chunk * 128 + tid;
        float* dst = nrm + ((size_t)cloud * 8 + b) * 3 * NPTS;
        dst[0 * NPTS + qg2] = nv[0];
        dst[1 * NPTS + qg2] = nv[1];
        dst[2 * NPTS + qg2] = nv[2];
    }
}

__global__ __launch_bounds__(256) void loss_kernel(const float* __restrict__ nrm,
                                                   float* __restrict__ out) {
    const int n = NRM_N;
    const float* a = nrm;
    const float* b = nrm + n;
    float acc = 0.f;
    for (int i = blockIdx.x * 256 + threadIdx.x; i < n; i += gridDim.x * 256) {
        float dd = a[i] - b[i];
        acc = fmaf(dd, dd, acc);
    }
#pragma unroll
    for (int off = 32; off > 0; off >>= 1) acc += __shfl_down(acc, off);
    __shared__ float wsum[4];
    int lane = threadIdx.x & 63, wv = threadIdx.x >> 6;
    if (lane == 0) wsum[wv] = acc;
    __syncthreads();
    if (threadIdx.x == 0) {
        float t = wsum[0] + wsum[1] + wsum[2] + wsum[3];
        atomicAdd(out, t * (1.f / (float)n));
    }
}

extern "C" void kernel_launch(void* const* d_in, const int* in_sizes, int n_in,
                              void* d_out, int out_size, void* d_ws, size_t ws_size,
                              hipStream_t stream) {
    (void)in_sizes; (void)n_in; (void)out_size;
    const float* pred = (const float*)d_in[0];
    const float* gt   = (const float*)d_in[1];
    float* out = (float*)d_out;

    size_t need = (size_t)2 * NRM_N * sizeof(float);
    float* nrm = (float*)d_ws;

    // gate: allow 78336 B of dynamic LDS per workgroup (R12: launch verified OK)
    int dev = 0;
    hipGetDevice(&dev);
    int maxShm = 0;
    hipDeviceGetAttribute(&maxShm, hipDeviceAttributeMaxSharedMemoryPerBlock, dev);
    hipError_t eAttr = hipFuncSetAttribute(
        reinterpret_cast<const void*>(normals4_kernel),
        hipFuncAttributeMaxDynamicSharedMemorySize, DYN_BYTES);
    bool use4 = (ws_size >= need) && ((maxShm >= DYN_BYTES) || (eAttr == hipSuccess));

    if (use4) {
        hipLaunchKernelGGL(normals4_kernel, dim3(512), dim3(512), DYN_BYTES, stream,
                           pred, gt, nrm, out);
        hipLaunchKernelGGL(loss_kernel, dim3(96), dim3(256), 0, stream, nrm, out);
    } else {
        hipLaunchKernelGGL(normals_kernel, dim3(512), dim3(512), 0, stream,
                           pred, gt, nrm, out);
        hipLaunchKernelGGL(loss_kernel, dim3(96), dim3(256), 0, stream, nrm, out);
    }
}